// Round 1
// 335.978 us; speedup vs baseline: 1.0980x; 1.0980x over previous
//
#include <hip/hip_runtime.h>

// TxModel: B=16384, K=64 tokens, DIN=49, D=16, NH=2, HD=8, FF=32
// Block = 256 threads = 4 waves, one batch element; wave w owns M-tile w.
// R5: VALU-bound (VALUBusy 75%, MfmaUtil 6.6%) -> cut VALU instruction count:
//  (1) x staged as RAW fp32 flat (pure float4 copy, no per-element div/swizzle/
//      cvt); bf16 conversion moved to proj fragment read (ds_read_b32 x16,
//      2-way banks = free).
//  (2) x region (12.6KB) is dead after proj -> KR/VTB/P alias into it behind an
//      extra barrier; total LDS unchanged (21776 B -> 7 blocks/CU).
//  (3) P relayout: 144B row stride + chunk^g XOR -> conflict-free b128 PV reads,
//      2-way writes, one write base + compile-time immediate offsets.
//  (4) softmax scale folded into k at qkv write (bias pre-scaled in prologue).
//  (5) v_rcp for softmax normalize; native exp2/rsq builtins; ds_swizzle
//      immediates replace __shfl_xor/__shfl (no lane-address VALU).

#define SCALE 0.510069729f   // log2(e)/sqrt(8)

// LDS layout (short indices; region R = bytes [0,16640)):
//   stage/proj phase: XF = fp32 x flat, 3136 + 16 pad floats (12608 B) at R+0
//   post-proj phase:  KR  [64][40] bf16 k rows        shorts [0,2560)
//                     VTB [16][72] bf16 v^T           shorts [2560,3712)
//                     PR  [64][72] bf16 P, chunk^g    shorts [3712,8320)
// HR  [64][40] bf16 h/q/ctx/hln/ff rows (cols 16..31 zeroed)  [8320,10880)
// RED 4 floats                                                 [10880,10888)
#define KRS   40
#define VTB   2560
#define VTS   72
#define PRB   3712
#define PRS   72
#define HRB   8320
#define HRS   40
#define RED   10880
#define SMTOT 10888

// ws layout (floats): [0,2304) 9 weight B-frags (v8bf: frag*64+lane)
//                     [2304,3328) hbias [w][r][lane] = proj_b[c]+pos[tok][c]
//                     [3328,3584) epil  [c][16]   (ep[1] pre-scaled by SCALE)
#define WS_HB   2304
#define WS_EP   3328

typedef __bf16 v8bf __attribute__((ext_vector_type(8)));
typedef float  v4f  __attribute__((ext_vector_type(4)));

#define LDS_ORDER() __asm__ volatile("" ::: "memory")

static __device__ __forceinline__ short f2bs(float f) {
    __bf16 h = (__bf16)f;
    return __builtin_bit_cast(short, h);
}
#define MFMA(a,b,c) __builtin_amdgcn_mfma_f32_16x16x32_bf16((a),(b),(c),0,0,0)

// ds_swizzle with compile-time pattern: no lane-address VALU.
// xor-butterfly m: (m<<10)|0x1F ; broadcast (lane&48)|N: (N<<5)|0x10
template<int IMM> static __device__ __forceinline__ float swz(float x) {
    return __builtin_bit_cast(float,
        __builtin_amdgcn_ds_swizzle(__builtin_bit_cast(int, x), IMM));
}

static __device__ __forceinline__ void red16(v4f& v) {
    #pragma unroll
    for (int r = 0; r < 4; ++r) v[r] += swz<0x041F>(v[r]);
    #pragma unroll
    for (int r = 0; r < 4; ++r) v[r] += swz<0x081F>(v[r]);
    #pragma unroll
    for (int r = 0; r < 4; ++r) v[r] += swz<0x101F>(v[r]);
    #pragma unroll
    for (int r = 0; r < 4; ++r) v[r] += swz<0x201F>(v[r]);
}

__global__ __launch_bounds__(64)
void tx_prep(const float* __restrict__ proj_w, const float* __restrict__ proj_b,
             const float* __restrict__ pos,
             const float* __restrict__ in_proj_w, const float* __restrict__ in_proj_b,
             const float* __restrict__ out_w, const float* __restrict__ out_b,
             const float* __restrict__ ln1_g, const float* __restrict__ ln1_b,
             const float* __restrict__ lin1_w, const float* __restrict__ lin1_b,
             const float* __restrict__ lin2_w, const float* __restrict__ lin2_b,
             const float* __restrict__ ln2_g, const float* __restrict__ ln2_b,
             const float* __restrict__ head_w, float* __restrict__ ws)
{
    const int lane = threadIdx.x, g = lane >> 4, c = lane & 15;
    v8bf* wf = (v8bf*)ws;
    v8bf F;
    #pragma unroll
    for (int j = 0; j < 8; ++j) F[j] = (__bf16)proj_w[c*49 + g*8 + j];
    wf[0*64 + lane] = F;
    #pragma unroll
    for (int j = 0; j < 8; ++j) { int k = 32 + g*8 + j; F[j] = (k < 49) ? (__bf16)proj_w[c*49 + k] : (__bf16)0.f; }
    wf[1*64 + lane] = F;
    #pragma unroll
    for (int nt = 0; nt < 3; ++nt) {
        #pragma unroll
        for (int j = 0; j < 8; ++j) { int k = g*8 + j; F[j] = (k < 16) ? (__bf16)in_proj_w[(nt*16 + c)*16 + k] : (__bf16)0.f; }
        wf[(2 + nt)*64 + lane] = F;
    }
    #pragma unroll
    for (int j = 0; j < 8; ++j) { int k = g*8 + j; F[j] = (k < 16) ? (__bf16)out_w[c*16 + k] : (__bf16)0.f; }
    wf[5*64 + lane] = F;
    #pragma unroll
    for (int nt = 0; nt < 2; ++nt) {
        #pragma unroll
        for (int j = 0; j < 8; ++j) { int k = g*8 + j; F[j] = (k < 16) ? (__bf16)lin1_w[(nt*16 + c)*16 + k] : (__bf16)0.f; }
        wf[(6 + nt)*64 + lane] = F;
    }
    #pragma unroll
    for (int j = 0; j < 8; ++j) F[j] = (__bf16)lin2_w[c*32 + g*8 + j];
    wf[8*64 + lane] = F;

    float* hb = ws + WS_HB;
    #pragma unroll
    for (int ww = 0; ww < 4; ++ww)
        #pragma unroll
        for (int r = 0; r < 4; ++r)
            hb[ww*256 + r*64 + lane] = proj_b[c] + pos[(ww*16 + g*4 + r)*16 + c];

    if (lane < 16) {
        float* ep = ws + WS_EP + lane*16;
        ep[0]  = in_proj_b[lane];              // q bias
        ep[1]  = in_proj_b[16 + lane] * SCALE; // k bias, pre-scaled (R5)
        ep[2]  = in_proj_b[32 + lane];         // v bias
        ep[3]  = out_b[lane];
        ep[4]  = ln1_g[lane];
        ep[5]  = ln1_b[lane];
        ep[6]  = lin1_b[lane];
        ep[7]  = lin1_b[16 + lane];
        ep[8]  = lin2_b[lane];
        ep[9]  = ln2_g[lane];
        ep[10] = ln2_b[lane];
        ep[11] = head_w[lane];
        ep[12] = 0.f; ep[13] = 0.f; ep[14] = 0.f; ep[15] = 0.f;
    }
}

__global__ __launch_bounds__(256, 7)
void tx_main(const float* __restrict__ x, const float* __restrict__ ws,
             const float* __restrict__ head_b, float* __restrict__ out)
{
    __shared__ __align__(16) short sm[SMTOT];
    const int tid   = threadIdx.x;
    const int w     = tid >> 6;
    const int lane  = tid & 63;
    const int g     = lane >> 4;
    const int c     = lane & 15;
    const int b     = blockIdx.x;
    const int myrow = w*16 + c;
    const int tok0  = w*16 + g*4;
    const v8bf* wf  = (const v8bf*)ws;
    const float4* ep4 = (const float4*)(ws + WS_EP);
    float* smf = (float*)sm;

    v8bf zfrag;
    #pragma unroll
    for (int j = 0; j < 8; ++j) zfrag[j] = (__bf16)0.f;
    const v4f zacc = {0.f, 0.f, 0.f, 0.f};

    // ---- stage x -> LDS, raw fp32 flat copy (zero per-element math) ----
    const float4* xb4 = (const float4*)(x + (size_t)b * 3136);
    float4* sf4 = (float4*)smf;
    #pragma unroll
    for (int i = 0; i < 3; ++i) sf4[tid + i*256] = xb4[tid + i*256];
    if (tid < 16)      sf4[768 + tid] = xb4[768 + tid];
    else if (tid < 32) smf[3136 + tid - 16] = 0.f;   // finite pad (NaN guard)
    // zero HR cols 16..31 of my row (K-pad; uninit LDS may be NaN)
    *(unsigned long long*)&sm[HRB + myrow*HRS + 16 + g*4] = 0ull;
    __syncthreads();

    // ---- proj: h = x @ proj_w^T (+ prebaked proj_b+pos), fp32 C-layout ----
    // A-frags read from flat fp32 rows; cols >=49 hit next row / pad but the
    // prologue zeroed proj_w frags for k>=49, so garbage*0 = 0.
    v4f hC;
    {
        const float* xr = smf + myrow*49 + g*8;
        v8bf a0, a1;
        #pragma unroll
        for (int j = 0; j < 8; ++j) a0[j] = (__bf16)xr[j];
        #pragma unroll
        for (int j = 0; j < 8; ++j) a1[j] = (__bf16)xr[32 + j];
        v8bf Bp0 = wf[0*64 + lane], Bp1 = wf[1*64 + lane];
        hC = MFMA(a0, Bp0, zacc);
        hC = MFMA(a1, Bp1, hC);
        const float* hb = ws + WS_HB;
        #pragma unroll
        for (int r = 0; r < 4; ++r) hC[r] += hb[w*256 + r*64 + lane];
        #pragma unroll
        for (int r = 0; r < 4; ++r) sm[HRB + (tok0 + r)*HRS + c] = f2bs(hC[r]);
    }
    __syncthreads();   // x fp32 region dead; KR/VTB/PR may overwrite it now

    // ---- qkv = h @ in_proj_w^T + b  (k pre-scaled by SCALE) ----
    {
        v8bf Bq0 = wf[2*64 + lane], Bq1 = wf[3*64 + lane], Bq2 = wf[4*64 + lane];
        v8bf a = *(const v8bf*)&sm[HRB + myrow*HRS + g*8];
        v4f qC = MFMA(a, Bq0, zacc);
        v4f kC = MFMA(a, Bq1, zacc);
        v4f vC = MFMA(a, Bq2, zacc);
        float4 e0 = ep4[c*4];
        #pragma unroll
        for (int r = 0; r < 4; ++r) {
            int tok = tok0 + r;
            sm[HRB + tok*HRS + c] = f2bs(qC[r] + e0.x);
            sm[tok*KRS + c]       = f2bs(fmaf(kC[r], SCALE, e0.y));
            sm[VTB + c*VTS + tok] = f2bs(vC[r] + e0.z);
        }
    }
    __syncthreads();

    // ---- attention: scores->exp->P (144B stride, chunk^g swizzle) -> PV ----
    v4f ctxC0, ctxC1;
    {
        v8bf aq = *(const v8bf*)&sm[HRB + myrow*HRS + g*8];  // cols 16..31 zero
        const int ch  = c >> 3;
        const int pwb = PRB + tok0*PRS + (c & 7);            // write base
        const int prd = PRB + myrow*PRS + ((g ^ ((myrow >> 2) & 3)) << 3);
        #pragma unroll
        for (int hh = 0; hh < 2; ++hh) {
            v4f sC[4];
            #pragma unroll
            for (int tj = 0; tj < 4; ++tj) {
                v8bf bk = zfrag;
                if (g == hh) bk = *(const v8bf*)&sm[(tj*16 + c)*KRS + g*8];
                sC[tj] = MFMA(aq, bk, zacc);
            }
            #pragma unroll
            for (int tj = 0; tj < 4; ++tj) {
                int po = pwb + (((tj*2 + ch) ^ g) << 3);
                #pragma unroll
                for (int r = 0; r < 4; ++r)
                    sm[po + r*PRS] = f2bs(__builtin_amdgcn_exp2f(sC[tj][r]));
            }
            v8bf bv0 = zfrag, bv1 = zfrag;
            bool act  = (hh == 0) ? (c < 8) : (c >= 8);
            int  onec = (hh == 0) ? 8 : 7;
            if (act) {
                bv0 = *(const v8bf*)&sm[VTB + c*VTS + g*8];
                bv1 = *(const v8bf*)&sm[VTB + c*VTS + 32 + g*8];
            } else if (c == onec) {
                #pragma unroll
                for (int j = 0; j < 8; ++j) { bv0[j] = (__bf16)1.f; bv1[j] = (__bf16)1.f; }
            }
            LDS_ORDER();
            v4f acc = zacc;
            acc = MFMA(*(const v8bf*)&sm[prd],      bv0, acc);
            acc = MFMA(*(const v8bf*)&sm[prd + 32], bv1, acc);
            if (hh) ctxC1 = acc; else ctxC0 = acc;
            LDS_ORDER();
        }
    }

    // ---- softmax normalize (l broadcast via ds_swizzle; v_rcp not div) ----
    {
        #pragma unroll
        for (int r = 0; r < 4; ++r) {
            float l0 = swz<0x110>(ctxC0[r]);   // from lane (lane&48)|8
            float l1 = swz<0x0F0>(ctxC1[r]);   // from lane (lane&48)|7
            float num = (c < 8) ? ctxC0[r] : ctxC1[r];
            float den = (c < 8) ? l0 : l1;
            sm[HRB + (tok0 + r)*HRS + c] = f2bs(num * __builtin_amdgcn_rcpf(den));
        }
    }
    LDS_ORDER();

    // ---- out-proj + residual + LN1 (C-layout swizzle butterflies) ----
    v4f hln;
    {
        v8bf Bo = wf[5*64 + lane];
        v8bf a = *(const v8bf*)&sm[HRB + myrow*HRS + g*8];
        v4f oC = MFMA(a, Bo, zacc);
        float4 e0 = ep4[c*4];
        float4 e1 = ep4[c*4 + 1];
        v4f hn;
        #pragma unroll
        for (int r = 0; r < 4; ++r) hn[r] = hC[r] + oC[r] + e0.w;
        v4f s = hn;
        red16(s);
        v4f t, vs;
        #pragma unroll
        for (int r = 0; r < 4; ++r) { t[r] = hn[r] - s[r]*0.0625f; vs[r] = t[r]*t[r]; }
        red16(vs);
        #pragma unroll
        for (int r = 0; r < 4; ++r) {
            float is = __builtin_amdgcn_rsqf(fmaf(vs[r], 0.0625f, 1e-5f));
            hln[r] = t[r]*is*e1.x + e1.y;
            sm[HRB + (tok0 + r)*HRS + c] = f2bs(hln[r]);
        }
    }
    LDS_ORDER();

    // ---- FFN: lin1(+bias,relu) -> lin2 (K=32) ----
    v4f o2;
    {
        v8bf Bl10 = wf[6*64 + lane], Bl11 = wf[7*64 + lane], Bl2 = wf[8*64 + lane];
        v8bf a = *(const v8bf*)&sm[HRB + myrow*HRS + g*8];
        v4f f0 = MFMA(a, Bl10, zacc);
        v4f f1 = MFMA(a, Bl11, zacc);
        float4 e1 = ep4[c*4 + 1];
        #pragma unroll
        for (int r = 0; r < 4; ++r) {
            int tok = tok0 + r;
            sm[HRB + tok*HRS + c]      = f2bs(fmaxf(f0[r] + e1.z, 0.f));
            sm[HRB + tok*HRS + 16 + c] = f2bs(fmaxf(f1[r] + e1.w, 0.f));
        }
        LDS_ORDER();
        v8bf a2 = *(const v8bf*)&sm[HRB + myrow*HRS + g*8];
        o2 = MFMA(a2, Bl2, zacc);
    }

    // ---- +lin2_b, residual, LN2, head dot; wave + cross-wave reduce ----
    float part = 0.f;
    {
        float4 e2 = ep4[c*4 + 2];
        v4f hn;
        #pragma unroll
        for (int r = 0; r < 4; ++r) hn[r] = hln[r] + o2[r] + e2.x;
        v4f s = hn;
        red16(s);
        v4f t, vs;
        #pragma unroll
        for (int r = 0; r < 4; ++r) { t[r] = hn[r] - s[r]*0.0625f; vs[r] = t[r]*t[r]; }
        red16(vs);
        #pragma unroll
        for (int r = 0; r < 4; ++r) {
            float is = __builtin_amdgcn_rsqf(fmaf(vs[r], 0.0625f, 1e-5f));
            float h3 = t[r]*is*e2.y + e2.z;
            part = fmaf(h3, e2.w, part);
        }
    }
    part += swz<0x041F>(part);
    part += swz<0x081F>(part);
    part += swz<0x101F>(part);
    part += swz<0x201F>(part);
    part += swz<0x401F>(part);
    part += __shfl_xor(part, 32, 64);
    float* fred = (float*)&sm[RED];
    if (lane == 0) fred[w] = part;
    __syncthreads();
    if (tid == 0)
        out[b] = (fred[0] + fred[1] + fred[2] + fred[3]) * (1.f/64.f) + head_b[0];
}

extern "C" void kernel_launch(void* const* d_in, const int* in_sizes, int n_in,
                              void* d_out, int out_size, void* d_ws, size_t ws_size,
                              hipStream_t stream) {
    const float* x         = (const float*)d_in[0];
    const float* proj_w    = (const float*)d_in[1];
    const float* proj_b    = (const float*)d_in[2];
    const float* pos       = (const float*)d_in[3];
    const float* in_proj_w = (const float*)d_in[4];
    const float* in_proj_b = (const float*)d_in[5];
    const float* out_w     = (const float*)d_in[6];
    const float* out_b     = (const float*)d_in[7];
    const float* ln1_g     = (const float*)d_in[8];
    const float* ln1_b     = (const float*)d_in[9];
    const float* lin1_w    = (const float*)d_in[10];
    const float* lin1_b    = (const float*)d_in[11];
    const float* lin2_w    = (const float*)d_in[12];
    const float* lin2_b    = (const float*)d_in[13];
    const float* ln2_g     = (const float*)d_in[14];
    const float* ln2_b     = (const float*)d_in[15];
    const float* head_w    = (const float*)d_in[16];
    const float* head_b    = (const float*)d_in[17];
    float* ws = (float*)d_ws;

    tx_prep<<<1, 64, 0, stream>>>(proj_w, proj_b, pos, in_proj_w, in_proj_b,
                                  out_w, out_b, ln1_g, ln1_b, lin1_w, lin1_b,
                                  lin2_w, lin2_b, ln2_g, ln2_b, head_w, ws);
    tx_main<<<16384, 256, 0, stream>>>(x, ws, head_b, (float*)d_out);
}

// Round 2
// 332.804 us; speedup vs baseline: 1.1084x; 1.0095x over previous
//
#include <hip/hip_runtime.h>

// TxModel: B=16384, K=64 tokens, DIN=49, D=16, NH=2, HD=8, FF=32
// Block = 256 threads = 4 waves, one batch element; wave w owns M-tile w.
// R6: occupancy push 7->8 blocks/CU + serial-depth cuts:
//  (1) KR shrunk [64][40]->[64][24] shorts (K only has 16 features; 24 keeps
//      48B rows = 16B-aligned b128 reads, conflict-free-ish banks).
//      LDS 21776 -> 19728 B -> 8 blocks/CU (+14% wave supply).
//  (2) hbias relayout in ws: proj bias+pos arrives as ONE global_load_dwordx4
//      per lane instead of 4 strided scalar loads.
//  (3) Both LNs use E[x^2]-E[x]^2: the two 4-stage swizzle reductions become
//      independent chains (compiler interleaves) -> ~130 cyc less serial depth
//      per LN, same op count.
// Carried from R5: raw-fp32 x staging, region aliasing behind barrier,
// 144B-stride swizzled P, scale folded into k, rcp/exp2/rsq natives,
// ds_swizzle-immediate reductions.

#define SCALE 0.510069729f   // log2(e)/sqrt(8)

// LDS layout (short indices):
//   stage/proj phase: XF = fp32 x flat, 3136 + 16 pad floats = bytes [0,12608)
//   post-proj phase:  KR  [64][24] bf16 k rows    shorts [0,1536)
//                     VTB [16][72] bf16 v^T       shorts [1536,2688)
//                     PR  [64][72] bf16 P chunk^g shorts [2688,7296)
// HR  [64][40] bf16 h/q/ctx/hln/ff rows (cols 16..31 zeroed)  [7296,9856)
//     (HR byte base 14592 >= 12608 -> never aliases XF)
// RED 4 floats                                                 [9856,9864)
#define KRS   24
#define VTB   1536
#define VTS   72
#define PRB   2688
#define PRS   72
#define HRB   7296
#define HRS   40
#define RED   9856
#define SMTOT 9864   // 19728 B -> 8 blocks/CU

// ws layout (floats): [0,2304) 9 weight B-frags (v8bf: frag*64+lane)
//                     [2304,3328) hbias [w][lane][r] = proj_b[c]+pos[tok][c]
//                     [3328,3584) epil  [c][16]   (ep[1] pre-scaled by SCALE)
#define WS_HB   2304
#define WS_EP   3328

typedef __bf16 v8bf __attribute__((ext_vector_type(8)));
typedef float  v4f  __attribute__((ext_vector_type(4)));

#define LDS_ORDER() __asm__ volatile("" ::: "memory")

static __device__ __forceinline__ short f2bs(float f) {
    __bf16 h = (__bf16)f;
    return __builtin_bit_cast(short, h);
}
#define MFMA(a,b,c) __builtin_amdgcn_mfma_f32_16x16x32_bf16((a),(b),(c),0,0,0)

// ds_swizzle with compile-time pattern: no lane-address VALU.
// xor-butterfly m: (m<<10)|0x1F ; broadcast (lane&48)|N: (N<<5)|0x10
template<int IMM> static __device__ __forceinline__ float swz(float x) {
    return __builtin_bit_cast(float,
        __builtin_amdgcn_ds_swizzle(__builtin_bit_cast(int, x), IMM));
}

static __device__ __forceinline__ void red16(v4f& v) {
    #pragma unroll
    for (int r = 0; r < 4; ++r) v[r] += swz<0x041F>(v[r]);
    #pragma unroll
    for (int r = 0; r < 4; ++r) v[r] += swz<0x081F>(v[r]);
    #pragma unroll
    for (int r = 0; r < 4; ++r) v[r] += swz<0x101F>(v[r]);
    #pragma unroll
    for (int r = 0; r < 4; ++r) v[r] += swz<0x201F>(v[r]);
}

__global__ __launch_bounds__(64)
void tx_prep(const float* __restrict__ proj_w, const float* __restrict__ proj_b,
             const float* __restrict__ pos,
             const float* __restrict__ in_proj_w, const float* __restrict__ in_proj_b,
             const float* __restrict__ out_w, const float* __restrict__ out_b,
             const float* __restrict__ ln1_g, const float* __restrict__ ln1_b,
             const float* __restrict__ lin1_w, const float* __restrict__ lin1_b,
             const float* __restrict__ lin2_w, const float* __restrict__ lin2_b,
             const float* __restrict__ ln2_g, const float* __restrict__ ln2_b,
             const float* __restrict__ head_w, float* __restrict__ ws)
{
    const int lane = threadIdx.x, g = lane >> 4, c = lane & 15;
    v8bf* wf = (v8bf*)ws;
    v8bf F;
    #pragma unroll
    for (int j = 0; j < 8; ++j) F[j] = (__bf16)proj_w[c*49 + g*8 + j];
    wf[0*64 + lane] = F;
    #pragma unroll
    for (int j = 0; j < 8; ++j) { int k = 32 + g*8 + j; F[j] = (k < 49) ? (__bf16)proj_w[c*49 + k] : (__bf16)0.f; }
    wf[1*64 + lane] = F;
    #pragma unroll
    for (int nt = 0; nt < 3; ++nt) {
        #pragma unroll
        for (int j = 0; j < 8; ++j) { int k = g*8 + j; F[j] = (k < 16) ? (__bf16)in_proj_w[(nt*16 + c)*16 + k] : (__bf16)0.f; }
        wf[(2 + nt)*64 + lane] = F;
    }
    #pragma unroll
    for (int j = 0; j < 8; ++j) { int k = g*8 + j; F[j] = (k < 16) ? (__bf16)out_w[c*16 + k] : (__bf16)0.f; }
    wf[5*64 + lane] = F;
    #pragma unroll
    for (int nt = 0; nt < 2; ++nt) {
        #pragma unroll
        for (int j = 0; j < 8; ++j) { int k = g*8 + j; F[j] = (k < 16) ? (__bf16)lin1_w[(nt*16 + c)*16 + k] : (__bf16)0.f; }
        wf[(6 + nt)*64 + lane] = F;
    }
    #pragma unroll
    for (int j = 0; j < 8; ++j) F[j] = (__bf16)lin2_w[c*32 + g*8 + j];
    wf[8*64 + lane] = F;

    // hbias: [w][lane][r] so main does ONE dwordx4 per lane (R6)
    float* hb = ws + WS_HB;
    #pragma unroll
    for (int ww = 0; ww < 4; ++ww)
        #pragma unroll
        for (int r = 0; r < 4; ++r)
            hb[ww*256 + lane*4 + r] = proj_b[c] + pos[(ww*16 + g*4 + r)*16 + c];

    if (lane < 16) {
        float* ep = ws + WS_EP + lane*16;
        ep[0]  = in_proj_b[lane];              // q bias
        ep[1]  = in_proj_b[16 + lane] * SCALE; // k bias, pre-scaled
        ep[2]  = in_proj_b[32 + lane];         // v bias
        ep[3]  = out_b[lane];
        ep[4]  = ln1_g[lane];
        ep[5]  = ln1_b[lane];
        ep[6]  = lin1_b[lane];
        ep[7]  = lin1_b[16 + lane];
        ep[8]  = lin2_b[lane];
        ep[9]  = ln2_g[lane];
        ep[10] = ln2_b[lane];
        ep[11] = head_w[lane];
        ep[12] = 0.f; ep[13] = 0.f; ep[14] = 0.f; ep[15] = 0.f;
    }
}

__global__ __launch_bounds__(256, 8)
void tx_main(const float* __restrict__ x, const float* __restrict__ ws,
             const float* __restrict__ head_b, float* __restrict__ out)
{
    __shared__ __align__(16) short sm[SMTOT];
    const int tid   = threadIdx.x;
    const int w     = tid >> 6;
    const int lane  = tid & 63;
    const int g     = lane >> 4;
    const int c     = lane & 15;
    const int b     = blockIdx.x;
    const int myrow = w*16 + c;
    const int tok0  = w*16 + g*4;
    const v8bf* wf  = (const v8bf*)ws;
    const float4* ep4 = (const float4*)(ws + WS_EP);
    float* smf = (float*)sm;

    v8bf zfrag;
    #pragma unroll
    for (int j = 0; j < 8; ++j) zfrag[j] = (__bf16)0.f;
    const v4f zacc = {0.f, 0.f, 0.f, 0.f};

    // ---- stage x -> LDS, raw fp32 flat copy (zero per-element math) ----
    const float4* xb4 = (const float4*)(x + (size_t)b * 3136);
    float4* sf4 = (float4*)smf;
    #pragma unroll
    for (int i = 0; i < 3; ++i) sf4[tid + i*256] = xb4[tid + i*256];
    if (tid < 16)      sf4[768 + tid] = xb4[768 + tid];
    else if (tid < 32) smf[3136 + tid - 16] = 0.f;   // finite pad (NaN guard)
    // zero HR cols 16..31 of my row (K-pad; uninit LDS may be NaN)
    *(unsigned long long*)&sm[HRB + myrow*HRS + 16 + g*4] = 0ull;
    __syncthreads();

    // ---- proj: h = x @ proj_w^T (+ prebaked proj_b+pos), fp32 C-layout ----
    // Cols >=49 hit next row / pad but prologue zeroed proj_w frags for k>=49.
    v4f hC;
    {
        const float* xr = smf + myrow*49 + g*8;
        v8bf a0, a1;
        #pragma unroll
        for (int j = 0; j < 8; ++j) a0[j] = (__bf16)xr[j];
        #pragma unroll
        for (int j = 0; j < 8; ++j) a1[j] = (__bf16)xr[32 + j];
        v8bf Bp0 = wf[0*64 + lane], Bp1 = wf[1*64 + lane];
        hC = MFMA(a0, Bp0, zacc);
        hC = MFMA(a1, Bp1, hC);
        v4f hb = ((const v4f*)(ws + WS_HB))[w*64 + lane];   // one dwordx4 (R6)
        #pragma unroll
        for (int r = 0; r < 4; ++r) hC[r] += hb[r];
        #pragma unroll
        for (int r = 0; r < 4; ++r) sm[HRB + (tok0 + r)*HRS + c] = f2bs(hC[r]);
    }
    __syncthreads();   // x fp32 region dead; KR/VTB/PR may overwrite it now

    // ---- qkv = h @ in_proj_w^T + b  (k pre-scaled by SCALE) ----
    {
        v8bf Bq0 = wf[2*64 + lane], Bq1 = wf[3*64 + lane], Bq2 = wf[4*64 + lane];
        v8bf a = *(const v8bf*)&sm[HRB + myrow*HRS + g*8];
        v4f qC = MFMA(a, Bq0, zacc);
        v4f kC = MFMA(a, Bq1, zacc);
        v4f vC = MFMA(a, Bq2, zacc);
        float4 e0 = ep4[c*4];
        #pragma unroll
        for (int r = 0; r < 4; ++r) {
            int tok = tok0 + r;
            sm[HRB + tok*HRS + c] = f2bs(qC[r] + e0.x);
            sm[tok*KRS + c]       = f2bs(fmaf(kC[r], SCALE, e0.y));
            sm[VTB + c*VTS + tok] = f2bs(vC[r] + e0.z);
        }
    }
    __syncthreads();

    // ---- attention: scores->exp->P (144B stride, chunk^g swizzle) -> PV ----
    v4f ctxC0, ctxC1;
    {
        v8bf aq = *(const v8bf*)&sm[HRB + myrow*HRS + g*8];  // cols 16..31 zero
        const int ch  = c >> 3;
        const int pwb = PRB + tok0*PRS + (c & 7);            // write base
        const int prd = PRB + myrow*PRS + ((g ^ ((myrow >> 2) & 3)) << 3);
        #pragma unroll
        for (int hh = 0; hh < 2; ++hh) {
            v4f sC[4];
            #pragma unroll
            for (int tj = 0; tj < 4; ++tj) {
                v8bf bk = zfrag;
                if (g == hh) bk = *(const v8bf*)&sm[(tj*16 + c)*KRS + g*8];
                sC[tj] = MFMA(aq, bk, zacc);
            }
            #pragma unroll
            for (int tj = 0; tj < 4; ++tj) {
                int po = pwb + (((tj*2 + ch) ^ g) << 3);
                #pragma unroll
                for (int r = 0; r < 4; ++r)
                    sm[po + r*PRS] = f2bs(__builtin_amdgcn_exp2f(sC[tj][r]));
            }
            v8bf bv0 = zfrag, bv1 = zfrag;
            bool act  = (hh == 0) ? (c < 8) : (c >= 8);
            int  onec = (hh == 0) ? 8 : 7;
            if (act) {
                bv0 = *(const v8bf*)&sm[VTB + c*VTS + g*8];
                bv1 = *(const v8bf*)&sm[VTB + c*VTS + 32 + g*8];
            } else if (c == onec) {
                #pragma unroll
                for (int j = 0; j < 8; ++j) { bv0[j] = (__bf16)1.f; bv1[j] = (__bf16)1.f; }
            }
            LDS_ORDER();
            v4f acc = zacc;
            acc = MFMA(*(const v8bf*)&sm[prd],      bv0, acc);
            acc = MFMA(*(const v8bf*)&sm[prd + 32], bv1, acc);
            if (hh) ctxC1 = acc; else ctxC0 = acc;
            LDS_ORDER();
        }
    }

    // ---- softmax normalize (l broadcast via ds_swizzle; v_rcp not div) ----
    {
        #pragma unroll
        for (int r = 0; r < 4; ++r) {
            float l0 = swz<0x110>(ctxC0[r]);   // from lane (lane&48)|8
            float l1 = swz<0x0F0>(ctxC1[r]);   // from lane (lane&48)|7
            float num = (c < 8) ? ctxC0[r] : ctxC1[r];
            float den = (c < 8) ? l0 : l1;
            sm[HRB + (tok0 + r)*HRS + c] = f2bs(num * __builtin_amdgcn_rcpf(den));
        }
    }
    LDS_ORDER();

    // ---- out-proj + residual + LN1 (E[x^2]-E[x]^2; independent reduces) ----
    v4f hln;
    {
        v8bf Bo = wf[5*64 + lane];
        v8bf a = *(const v8bf*)&sm[HRB + myrow*HRS + g*8];
        v4f oC = MFMA(a, Bo, zacc);
        float4 e0 = ep4[c*4];
        float4 e1 = ep4[c*4 + 1];
        v4f hn, s, q;
        #pragma unroll
        for (int r = 0; r < 4; ++r) { hn[r] = hC[r] + oC[r] + e0.w; s[r] = hn[r]; q[r] = hn[r]*hn[r]; }
        red16(s);
        red16(q);
        #pragma unroll
        for (int r = 0; r < 4; ++r) {
            float mean = s[r]*0.0625f;
            float var  = fmaf(q[r], 0.0625f, -mean*mean);
            float is = __builtin_amdgcn_rsqf(var + 1e-5f);
            hln[r] = (hn[r] - mean)*is*e1.x + e1.y;
            sm[HRB + (tok0 + r)*HRS + c] = f2bs(hln[r]);
        }
    }
    LDS_ORDER();

    // ---- FFN: lin1(+bias,relu) -> lin2 (K=32) ----
    v4f o2;
    {
        v8bf Bl10 = wf[6*64 + lane], Bl11 = wf[7*64 + lane], Bl2 = wf[8*64 + lane];
        v8bf a = *(const v8bf*)&sm[HRB + myrow*HRS + g*8];
        v4f f0 = MFMA(a, Bl10, zacc);
        v4f f1 = MFMA(a, Bl11, zacc);
        float4 e1 = ep4[c*4 + 1];
        #pragma unroll
        for (int r = 0; r < 4; ++r) {
            int tok = tok0 + r;
            sm[HRB + tok*HRS + c]      = f2bs(fmaxf(f0[r] + e1.z, 0.f));
            sm[HRB + tok*HRS + 16 + c] = f2bs(fmaxf(f1[r] + e1.w, 0.f));
        }
        LDS_ORDER();
        v8bf a2 = *(const v8bf*)&sm[HRB + myrow*HRS + g*8];
        o2 = MFMA(a2, Bl2, zacc);
    }

    // ---- +lin2_b, residual, LN2 (same var trick), head dot; reduce ----
    float part = 0.f;
    {
        float4 e2 = ep4[c*4 + 2];
        v4f hn, s, q;
        #pragma unroll
        for (int r = 0; r < 4; ++r) { hn[r] = hln[r] + o2[r] + e2.x; s[r] = hn[r]; q[r] = hn[r]*hn[r]; }
        red16(s);
        red16(q);
        #pragma unroll
        for (int r = 0; r < 4; ++r) {
            float mean = s[r]*0.0625f;
            float var  = fmaf(q[r], 0.0625f, -mean*mean);
            float is = __builtin_amdgcn_rsqf(var + 1e-5f);
            float h3 = (hn[r] - mean)*is*e2.y + e2.z;
            part = fmaf(h3, e2.w, part);
        }
    }
    part += swz<0x041F>(part);
    part += swz<0x081F>(part);
    part += swz<0x101F>(part);
    part += swz<0x201F>(part);
    part += swz<0x401F>(part);
    part += __shfl_xor(part, 32, 64);
    float* fred = (float*)&sm[RED];
    if (lane == 0) fred[w] = part;
    __syncthreads();
    if (tid == 0)
        out[b] = (fred[0] + fred[1] + fred[2] + fred[3]) * (1.f/64.f) + head_b[0];
}

extern "C" void kernel_launch(void* const* d_in, const int* in_sizes, int n_in,
                              void* d_out, int out_size, void* d_ws, size_t ws_size,
                              hipStream_t stream) {
    const float* x         = (const float*)d_in[0];
    const float* proj_w    = (const float*)d_in[1];
    const float* proj_b    = (const float*)d_in[2];
    const float* pos       = (const float*)d_in[3];
    const float* in_proj_w = (const float*)d_in[4];
    const float* in_proj_b = (const float*)d_in[5];
    const float* out_w     = (const float*)d_in[6];
    const float* out_b     = (const float*)d_in[7];
    const float* ln1_g     = (const float*)d_in[8];
    const float* ln1_b     = (const float*)d_in[9];
    const float* lin1_w    = (const float*)d_in[10];
    const float* lin1_b    = (const float*)d_in[11];
    const float* lin2_w    = (const float*)d_in[12];
    const float* lin2_b    = (const float*)d_in[13];
    const float* ln2_g     = (const float*)d_in[14];
    const float* ln2_b     = (const float*)d_in[15];
    const float* head_w    = (const float*)d_in[16];
    const float* head_b    = (const float*)d_in[17];
    float* ws = (float*)d_ws;

    tx_prep<<<1, 64, 0, stream>>>(proj_w, proj_b, pos, in_proj_w, in_proj_b,
                                  out_w, out_b, ln1_g, ln1_b, lin1_w, lin1_b,
                                  lin2_w, lin2_b, ln2_g, ln2_b, head_w, ws);
    tx_main<<<16384, 256, 0, stream>>>(x, ws, head_b, (float*)d_out);
}

// Round 3
// 327.885 us; speedup vs baseline: 1.1251x; 1.0150x over previous
//
#include <hip/hip_runtime.h>

// TxModel: B=16384, K=64 tokens, DIN=49, D=16, NH=2, HD=8, FF=32
// Block = 256 threads = 4 waves, one batch element; wave w owns M-tile w.
// R7: P matrix never touches LDS.
//  (1) Scores computed SWAPPED: MFMA(A=K-rows, B=Q masked per head). Lane
//      (g,c) then holds P[key=16t+4g+r][query=w16+c] for t=0..3 — with keys
//      stored PERMUTED in V^T (slot sigma(tok)=32(w>>1)+8g+4(w&1)+r, legal
//      since sum over keys is permutation-invariant), each lane's own scores
//      ARE its PV A-fragment slots. exp2 -> bf16 frag -> PV MFMA, zero
//      cross-lane traffic. Removes per lane: 32 ds_write_b16 + 4 ds_read_b128
//      + 2 fences + swizzled addr math; PR region (9.2KB LDS) deleted.
//  (2) KR cols 16..23 zeroed (swapped A-frags read them; stale bytes could be
//      NaN and NaN*0=NaN in MFMA). g=3 slice reads next row / VTB = finite,
//      killed by zero B rows 16..31.
//  (3) Biases/residuals folded into MFMA C-input: proj<-hbias, outproj<-hC,
//      lin2<-hln (-12 VALU adds).
// Carried: raw-fp32 x staging, region aliasing behind barrier, k pre-scaled,
// rcp/exp2/rsq natives, ds_swizzle-immediate reductions, E[x^2]-E[x]^2 LNs.

#define SCALE 0.510069729f   // log2(e)/sqrt(8)

// LDS layout (short indices):
//   stage/proj phase: XF = fp32 x flat, 3136+16 pad floats = shorts [0,6304)
//   post-proj phase:  KR  [64][24] bf16 k rows (cols 16..23 zeroed) [0,1536)
//                     VTB [16][72] bf16 v^T, slot-permuted       [1536,2688)
// HR  [64][40] bf16 h/q/ctx/hln/ff rows (cols 16..31 zeroed)     [6304,8864)
// RED 4 floats                                                   [8864,8872)
#define KRS   24
#define VTB   1536
#define VTS   72
#define HRB   6304
#define HRS   40
#define RED   8864
#define SMTOT 8872   // 17744 B

// ws layout (floats): [0,2304) 9 weight B-frags (v8bf: frag*64+lane)
//                     [2304,3328) hbias [w][lane][r] = proj_b[c]+pos[tok][c]
//                     [3328,3584) epil  [c][16]   (ep[1] pre-scaled by SCALE)
#define WS_HB   2304
#define WS_EP   3328

typedef __bf16 v8bf __attribute__((ext_vector_type(8)));
typedef float  v4f  __attribute__((ext_vector_type(4)));

#define LDS_ORDER() __asm__ volatile("" ::: "memory")

static __device__ __forceinline__ short f2bs(float f) {
    __bf16 h = (__bf16)f;
    return __builtin_bit_cast(short, h);
}
#define MFMA(a,b,c) __builtin_amdgcn_mfma_f32_16x16x32_bf16((a),(b),(c),0,0,0)

// ds_swizzle with compile-time pattern: no lane-address VALU.
// xor-butterfly m: (m<<10)|0x1F ; broadcast (lane&48)|N: (N<<5)|0x10
template<int IMM> static __device__ __forceinline__ float swz(float x) {
    return __builtin_bit_cast(float,
        __builtin_amdgcn_ds_swizzle(__builtin_bit_cast(int, x), IMM));
}

static __device__ __forceinline__ void red16(v4f& v) {
    #pragma unroll
    for (int r = 0; r < 4; ++r) v[r] += swz<0x041F>(v[r]);
    #pragma unroll
    for (int r = 0; r < 4; ++r) v[r] += swz<0x081F>(v[r]);
    #pragma unroll
    for (int r = 0; r < 4; ++r) v[r] += swz<0x101F>(v[r]);
    #pragma unroll
    for (int r = 0; r < 4; ++r) v[r] += swz<0x201F>(v[r]);
}

__global__ __launch_bounds__(64)
void tx_prep(const float* __restrict__ proj_w, const float* __restrict__ proj_b,
             const float* __restrict__ pos,
             const float* __restrict__ in_proj_w, const float* __restrict__ in_proj_b,
             const float* __restrict__ out_w, const float* __restrict__ out_b,
             const float* __restrict__ ln1_g, const float* __restrict__ ln1_b,
             const float* __restrict__ lin1_w, const float* __restrict__ lin1_b,
             const float* __restrict__ lin2_w, const float* __restrict__ lin2_b,
             const float* __restrict__ ln2_g, const float* __restrict__ ln2_b,
             const float* __restrict__ head_w, float* __restrict__ ws)
{
    const int lane = threadIdx.x, g = lane >> 4, c = lane & 15;
    v8bf* wf = (v8bf*)ws;
    v8bf F;
    #pragma unroll
    for (int j = 0; j < 8; ++j) F[j] = (__bf16)proj_w[c*49 + g*8 + j];
    wf[0*64 + lane] = F;
    #pragma unroll
    for (int j = 0; j < 8; ++j) { int k = 32 + g*8 + j; F[j] = (k < 49) ? (__bf16)proj_w[c*49 + k] : (__bf16)0.f; }
    wf[1*64 + lane] = F;
    #pragma unroll
    for (int nt = 0; nt < 3; ++nt) {
        #pragma unroll
        for (int j = 0; j < 8; ++j) { int k = g*8 + j; F[j] = (k < 16) ? (__bf16)in_proj_w[(nt*16 + c)*16 + k] : (__bf16)0.f; }
        wf[(2 + nt)*64 + lane] = F;
    }
    #pragma unroll
    for (int j = 0; j < 8; ++j) { int k = g*8 + j; F[j] = (k < 16) ? (__bf16)out_w[c*16 + k] : (__bf16)0.f; }
    wf[5*64 + lane] = F;
    #pragma unroll
    for (int nt = 0; nt < 2; ++nt) {
        #pragma unroll
        for (int j = 0; j < 8; ++j) { int k = g*8 + j; F[j] = (k < 16) ? (__bf16)lin1_w[(nt*16 + c)*16 + k] : (__bf16)0.f; }
        wf[(6 + nt)*64 + lane] = F;
    }
    #pragma unroll
    for (int j = 0; j < 8; ++j) F[j] = (__bf16)lin2_w[c*32 + g*8 + j];
    wf[8*64 + lane] = F;

    // hbias: [w][lane][r] so main does ONE dwordx4 per lane
    float* hb = ws + WS_HB;
    #pragma unroll
    for (int ww = 0; ww < 4; ++ww)
        #pragma unroll
        for (int r = 0; r < 4; ++r)
            hb[ww*256 + lane*4 + r] = proj_b[c] + pos[(ww*16 + g*4 + r)*16 + c];

    if (lane < 16) {
        float* ep = ws + WS_EP + lane*16;
        ep[0]  = in_proj_b[lane];              // q bias
        ep[1]  = in_proj_b[16 + lane] * SCALE; // k bias, pre-scaled
        ep[2]  = in_proj_b[32 + lane];         // v bias
        ep[3]  = out_b[lane];
        ep[4]  = ln1_g[lane];
        ep[5]  = ln1_b[lane];
        ep[6]  = lin1_b[lane];
        ep[7]  = lin1_b[16 + lane];
        ep[8]  = lin2_b[lane];
        ep[9]  = ln2_g[lane];
        ep[10] = ln2_b[lane];
        ep[11] = head_w[lane];
        ep[12] = 0.f; ep[13] = 0.f; ep[14] = 0.f; ep[15] = 0.f;
    }
}

__global__ __launch_bounds__(256, 8)
void tx_main(const float* __restrict__ x, const float* __restrict__ ws,
             const float* __restrict__ head_b, float* __restrict__ out)
{
    __shared__ __align__(16) short sm[SMTOT];
    const int tid   = threadIdx.x;
    const int w     = tid >> 6;
    const int lane  = tid & 63;
    const int g     = lane >> 4;
    const int c     = lane & 15;
    const int b     = blockIdx.x;
    const int myrow = w*16 + c;
    const int tok0  = w*16 + g*4;
    const v8bf* wf  = (const v8bf*)ws;
    const float4* ep4 = (const float4*)(ws + WS_EP);
    float* smf = (float*)sm;

    v8bf zfrag;
    #pragma unroll
    for (int j = 0; j < 8; ++j) zfrag[j] = (__bf16)0.f;
    const v4f zacc = {0.f, 0.f, 0.f, 0.f};

    // ---- stage x -> LDS, raw fp32 flat copy (zero per-element math) ----
    const float4* xb4 = (const float4*)(x + (size_t)b * 3136);
    float4* sf4 = (float4*)smf;
    #pragma unroll
    for (int i = 0; i < 3; ++i) sf4[tid + i*256] = xb4[tid + i*256];
    if (tid < 16)      sf4[768 + tid] = xb4[768 + tid];
    else if (tid < 32) smf[3136 + tid - 16] = 0.f;   // finite pad (NaN guard)
    // zero HR cols 16..31 of my row (K-pad; uninit LDS may be NaN)
    *(unsigned long long*)&sm[HRB + myrow*HRS + 16 + g*4] = 0ull;
    __syncthreads();

    // ---- proj: h = x @ proj_w^T, hbias folded into MFMA C-input ----
    v4f hC;
    {
        const float* xr = smf + myrow*49 + g*8;
        v8bf a0, a1;
        #pragma unroll
        for (int j = 0; j < 8; ++j) a0[j] = (__bf16)xr[j];
        #pragma unroll
        for (int j = 0; j < 8; ++j) a1[j] = (__bf16)xr[32 + j];
        v4f hb = ((const v4f*)(ws + WS_HB))[w*64 + lane];   // one dwordx4
        hC = MFMA(a0, wf[0*64 + lane], hb);
        hC = MFMA(a1, wf[1*64 + lane], hC);
        #pragma unroll
        for (int r = 0; r < 4; ++r) sm[HRB + (tok0 + r)*HRS + c] = f2bs(hC[r]);
    }
    __syncthreads();   // x fp32 region dead; KR/VTB may overwrite it now

    // ---- qkv = h @ in_proj_w^T + b; v written SLOT-PERMUTED ----
    {
        if (tid < 64) {   // KR cols 16..23 = 0 (read by swapped A-frags, g=2)
            float4 z4 = {0.f, 0.f, 0.f, 0.f};
            *(float4*)&sm[tid*KRS + 16] = z4;
        }
        v8bf a = *(const v8bf*)&sm[HRB + myrow*HRS + g*8];
        v4f qC = MFMA(a, wf[2*64 + lane], zacc);
        v4f kC = MFMA(a, wf[3*64 + lane], zacc);
        v4f vC = MFMA(a, wf[4*64 + lane], zacc);
        float4 e0 = ep4[c*4];
        const int vsl = VTB + c*VTS + 32*(w >> 1) + 8*g + 4*(w & 1);
        #pragma unroll
        for (int r = 0; r < 4; ++r) {
            int tok = tok0 + r;
            sm[HRB + tok*HRS + c] = f2bs(qC[r] + e0.x);
            sm[tok*KRS + c]       = f2bs(fmaf(kC[r], SCALE, e0.y));
            sm[vsl + r]           = f2bs(vC[r] + e0.z);
        }
    }
    __syncthreads();

    // ---- attention: swapped scores -> P in-register -> PV ----
    v4f ctxC0, ctxC1;
    {
        v8bf aq = *(const v8bf*)&sm[HRB + myrow*HRS + g*8];  // cols 16..31 zero
        #pragma unroll
        for (int hh = 0; hh < 2; ++hh) {
            v8bf bq = (g == hh) ? aq : zfrag;  // B rows = head hh's 8 features
            v8bf plo, phi;
            {
                v8bf ak0 = *(const v8bf*)&sm[(0*16 + c)*KRS + g*8];
                v8bf ak1 = *(const v8bf*)&sm[(1*16 + c)*KRS + g*8];
                v4f s0 = MFMA(ak0, bq, zacc);
                v4f s1 = MFMA(ak1, bq, zacc);
                #pragma unroll
                for (int r = 0; r < 4; ++r) {
                    plo[r]     = (__bf16)__builtin_amdgcn_exp2f(s0[r]);
                    plo[4 + r] = (__bf16)__builtin_amdgcn_exp2f(s1[r]);
                }
                v8bf ak2 = *(const v8bf*)&sm[(2*16 + c)*KRS + g*8];
                v8bf ak3 = *(const v8bf*)&sm[(3*16 + c)*KRS + g*8];
                v4f s2 = MFMA(ak2, bq, zacc);
                v4f s3 = MFMA(ak3, bq, zacc);
                #pragma unroll
                for (int r = 0; r < 4; ++r) {
                    phi[r]     = (__bf16)__builtin_amdgcn_exp2f(s2[r]);
                    phi[4 + r] = (__bf16)__builtin_amdgcn_exp2f(s3[r]);
                }
            }
            // V (slot-permuted) + ones column for softmax denominator
            v8bf bv0 = zfrag, bv1 = zfrag;
            bool act  = (hh == 0) ? (c < 8) : (c >= 8);
            int  onec = (hh == 0) ? 8 : 7;
            if (act) {
                bv0 = *(const v8bf*)&sm[VTB + c*VTS + g*8];
                bv1 = *(const v8bf*)&sm[VTB + c*VTS + 32 + g*8];
            } else if (c == onec) {
                #pragma unroll
                for (int j = 0; j < 8; ++j) { bv0[j] = (__bf16)1.f; bv1[j] = (__bf16)1.f; }
            }
            v4f acc = MFMA(plo, bv0, zacc);
            acc = MFMA(phi, bv1, acc);
            if (hh) ctxC1 = acc; else ctxC0 = acc;
        }
    }

    // ---- softmax normalize (l broadcast via ds_swizzle; v_rcp not div) ----
    {
        #pragma unroll
        for (int r = 0; r < 4; ++r) {
            float l0 = swz<0x110>(ctxC0[r]);   // from lane (lane&48)|8
            float l1 = swz<0x0F0>(ctxC1[r]);   // from lane (lane&48)|7
            float num = (c < 8) ? ctxC0[r] : ctxC1[r];
            float den = (c < 8) ? l0 : l1;
            sm[HRB + (tok0 + r)*HRS + c] = f2bs(num * __builtin_amdgcn_rcpf(den));
        }
    }
    LDS_ORDER();

    // ---- out-proj (+hC via C-input) + LN1 (E[x^2]-E[x]^2) ----
    v4f hln;
    {
        v8bf a = *(const v8bf*)&sm[HRB + myrow*HRS + g*8];
        v4f oC = MFMA(a, wf[5*64 + lane], hC);   // = hC + ctx@out_w^T
        float4 e0 = ep4[c*4];
        float4 e1 = ep4[c*4 + 1];
        v4f hn, s, q;
        #pragma unroll
        for (int r = 0; r < 4; ++r) { hn[r] = oC[r] + e0.w; s[r] = hn[r]; q[r] = hn[r]*hn[r]; }
        red16(s);
        red16(q);
        #pragma unroll
        for (int r = 0; r < 4; ++r) {
            float mean = s[r]*0.0625f;
            float var  = fmaf(q[r], 0.0625f, -mean*mean);
            float is = __builtin_amdgcn_rsqf(var + 1e-5f);
            hln[r] = (hn[r] - mean)*is*e1.x + e1.y;
            sm[HRB + (tok0 + r)*HRS + c] = f2bs(hln[r]);
        }
    }
    LDS_ORDER();

    // ---- FFN: lin1(+bias,relu) -> lin2 (K=32, hln folded into C) ----
    v4f o2;
    {
        v8bf a = *(const v8bf*)&sm[HRB + myrow*HRS + g*8];
        v4f f0 = MFMA(a, wf[6*64 + lane], zacc);
        v4f f1 = MFMA(a, wf[7*64 + lane], zacc);
        float4 e1 = ep4[c*4 + 1];
        #pragma unroll
        for (int r = 0; r < 4; ++r) {
            int tok = tok0 + r;
            sm[HRB + tok*HRS + c]      = f2bs(fmaxf(f0[r] + e1.z, 0.f));
            sm[HRB + tok*HRS + 16 + c] = f2bs(fmaxf(f1[r] + e1.w, 0.f));
        }
        LDS_ORDER();
        v8bf a2 = *(const v8bf*)&sm[HRB + myrow*HRS + g*8];
        o2 = MFMA(a2, wf[8*64 + lane], hln);     // = hln + ff@lin2_w^T
    }

    // ---- +lin2_b, LN2 (same var trick), head dot; wave + x-wave reduce ----
    float part = 0.f;
    {
        float4 e2 = ep4[c*4 + 2];
        v4f hn, s, q;
        #pragma unroll
        for (int r = 0; r < 4; ++r) { hn[r] = o2[r] + e2.x; s[r] = hn[r]; q[r] = hn[r]*hn[r]; }
        red16(s);
        red16(q);
        #pragma unroll
        for (int r = 0; r < 4; ++r) {
            float mean = s[r]*0.0625f;
            float var  = fmaf(q[r], 0.0625f, -mean*mean);
            float is = __builtin_amdgcn_rsqf(var + 1e-5f);
            float h3 = (hn[r] - mean)*is*e2.y + e2.z;
            part = fmaf(h3, e2.w, part);
        }
    }
    part += swz<0x041F>(part);
    part += swz<0x081F>(part);
    part += swz<0x101F>(part);
    part += swz<0x201F>(part);
    part += swz<0x401F>(part);
    part += __shfl_xor(part, 32, 64);
    float* fred = (float*)&sm[RED];
    if (lane == 0) fred[w] = part;
    __syncthreads();
    if (tid == 0)
        out[b] = (fred[0] + fred[1] + fred[2] + fred[3]) * (1.f/64.f) + head_b[0];
}

extern "C" void kernel_launch(void* const* d_in, const int* in_sizes, int n_in,
                              void* d_out, int out_size, void* d_ws, size_t ws_size,
                              hipStream_t stream) {
    const float* x         = (const float*)d_in[0];
    const float* proj_w    = (const float*)d_in[1];
    const float* proj_b    = (const float*)d_in[2];
    const float* pos       = (const float*)d_in[3];
    const float* in_proj_w = (const float*)d_in[4];
    const float* in_proj_b = (const float*)d_in[5];
    const float* out_w     = (const float*)d_in[6];
    const float* out_b     = (const float*)d_in[7];
    const float* ln1_g     = (const float*)d_in[8];
    const float* ln1_b     = (const float*)d_in[9];
    const float* lin1_w    = (const float*)d_in[10];
    const float* lin1_b    = (const float*)d_in[11];
    const float* lin2_w    = (const float*)d_in[12];
    const float* lin2_b    = (const float*)d_in[13];
    const float* ln2_g     = (const float*)d_in[14];
    const float* ln2_b     = (const float*)d_in[15];
    const float* head_w    = (const float*)d_in[16];
    const float* head_b    = (const float*)d_in[17];
    float* ws = (float*)d_ws;

    tx_prep<<<1, 64, 0, stream>>>(proj_w, proj_b, pos, in_proj_w, in_proj_b,
                                  out_w, out_b, ln1_g, ln1_b, lin1_w, lin1_b,
                                  lin2_w, lin2_b, ln2_g, ln2_b, head_w, ws);
    tx_main<<<16384, 256, 0, stream>>>(x, ws, head_b, (float*)d_out);
}

// Round 4
// 324.236 us; speedup vs baseline: 1.1377x; 1.0113x over previous
//
#include <hip/hip_runtime.h>

// TxModel: B=16384, K=64 tokens, DIN=49, D=16, NH=2, HD=8, FF=32
// Block = 256 threads = 4 waves, one batch element; wave w owns M-tile w.
// R8: x staging deleted; 2 of 3 barriers deleted.
//  (1) proj A-frags load x GLOBAL->REGISTER directly (each lane: 16 floats of
//      one row). Second K-chunk is bounds-safe via remapped weight frag:
//      slot (g,j) <-> k = {32+j, 40+j, (j==7?48:dead), dead} for g=0..3, and
//      A loads from col min(32+g*8,41) -> max index 63*49+48 = 3135, in
//      bounds, finite; dead slots hit zero weights. Over-read stays in the
//      row's cache lines -> no extra HBM traffic.
//  (2) fp32 x region gone -> stage barrier gone; post-proj barrier gone
//      (h->qkv is wave-local; LDS_ORDER suffices). ONE mid-kernel barrier
//      remains (k/V visibility for attention). KR col-zeroing wave-local.
//      LDS 17744 -> 10512 B.
//  (3) LN micro: is = rsq(fmaf(q,1/16, fmaf(mean,-mean,eps))) (-8 VALU).
// Carried: in-register P via swapped scores + slot-permuted V (R7), folded
// biases in MFMA C-inputs, k pre-scaled, rcp/exp2/rsq natives, ds_swizzle
// reductions, E[x^2]-E[x]^2 LNs.

#define SCALE 0.510069729f   // log2(e)/sqrt(8)

// LDS layout (short indices):
//   KR  [64][24] bf16 k rows (cols 16..23 zeroed)  [0,1536)
//   VTB [16][72] bf16 v^T, slot-permuted           [1536,2688)
//   HR  [64][40] bf16 h/q/ctx/hln/ff rows          [2688,5248)
//   RED 4 floats                                   [5248,5256)
#define KRS   24
#define VTB   1536
#define VTS   72
#define HRB   2688
#define HRS   40
#define RED   5248
#define SMTOT 5256   // 10512 B

// ws layout (floats): [0,2304) 9 weight B-frags (v8bf: frag*64+lane)
//                     [2304,3328) hbias [w][lane][r] = proj_b[c]+pos[tok][c]
//                     [3328,3584) epil  [c][16]   (ep[1] pre-scaled by SCALE)
#define WS_HB   2304
#define WS_EP   3328

typedef __bf16 v8bf __attribute__((ext_vector_type(8)));
typedef float  v4f  __attribute__((ext_vector_type(4)));

#define LDS_ORDER() __asm__ volatile("" ::: "memory")

static __device__ __forceinline__ short f2bs(float f) {
    __bf16 h = (__bf16)f;
    return __builtin_bit_cast(short, h);
}
#define MFMA(a,b,c) __builtin_amdgcn_mfma_f32_16x16x32_bf16((a),(b),(c),0,0,0)

// ds_swizzle with compile-time pattern: no lane-address VALU.
// xor-butterfly m: (m<<10)|0x1F ; broadcast (lane&48)|N: (N<<5)|0x10
template<int IMM> static __device__ __forceinline__ float swz(float x) {
    return __builtin_bit_cast(float,
        __builtin_amdgcn_ds_swizzle(__builtin_bit_cast(int, x), IMM));
}

static __device__ __forceinline__ void red16(v4f& v) {
    #pragma unroll
    for (int r = 0; r < 4; ++r) v[r] += swz<0x041F>(v[r]);
    #pragma unroll
    for (int r = 0; r < 4; ++r) v[r] += swz<0x081F>(v[r]);
    #pragma unroll
    for (int r = 0; r < 4; ++r) v[r] += swz<0x101F>(v[r]);
    #pragma unroll
    for (int r = 0; r < 4; ++r) v[r] += swz<0x201F>(v[r]);
}

__global__ __launch_bounds__(64)
void tx_prep(const float* __restrict__ proj_w, const float* __restrict__ proj_b,
             const float* __restrict__ pos,
             const float* __restrict__ in_proj_w, const float* __restrict__ in_proj_b,
             const float* __restrict__ out_w, const float* __restrict__ out_b,
             const float* __restrict__ ln1_g, const float* __restrict__ ln1_b,
             const float* __restrict__ lin1_w, const float* __restrict__ lin1_b,
             const float* __restrict__ lin2_w, const float* __restrict__ lin2_b,
             const float* __restrict__ ln2_g, const float* __restrict__ ln2_b,
             const float* __restrict__ head_w, float* __restrict__ ws)
{
    const int lane = threadIdx.x, g = lane >> 4, c = lane & 15;
    v8bf* wf = (v8bf*)ws;
    v8bf F;
    #pragma unroll
    for (int j = 0; j < 8; ++j) F[j] = (__bf16)proj_w[c*49 + g*8 + j];
    wf[0*64 + lane] = F;
    // wf[1]: remapped K-chunk2 (R8): g=0 -> k=32+j; g=1 -> k=40+j;
    // g=2 -> only j==7 live (k=48); g=3 -> all dead (zero).
    #pragma unroll
    for (int j = 0; j < 8; ++j) {
        int k = (g == 0) ? (32 + j) : (g == 1) ? (40 + j)
              : (g == 2 && j == 7) ? 48 : -1;
        F[j] = (k >= 0) ? (__bf16)proj_w[c*49 + k] : (__bf16)0.f;
    }
    wf[1*64 + lane] = F;
    #pragma unroll
    for (int nt = 0; nt < 3; ++nt) {
        #pragma unroll
        for (int j = 0; j < 8; ++j) { int k = g*8 + j; F[j] = (k < 16) ? (__bf16)in_proj_w[(nt*16 + c)*16 + k] : (__bf16)0.f; }
        wf[(2 + nt)*64 + lane] = F;
    }
    #pragma unroll
    for (int j = 0; j < 8; ++j) { int k = g*8 + j; F[j] = (k < 16) ? (__bf16)out_w[c*16 + k] : (__bf16)0.f; }
    wf[5*64 + lane] = F;
    #pragma unroll
    for (int nt = 0; nt < 2; ++nt) {
        #pragma unroll
        for (int j = 0; j < 8; ++j) { int k = g*8 + j; F[j] = (k < 16) ? (__bf16)lin1_w[(nt*16 + c)*16 + k] : (__bf16)0.f; }
        wf[(6 + nt)*64 + lane] = F;
    }
    #pragma unroll
    for (int j = 0; j < 8; ++j) F[j] = (__bf16)lin2_w[c*32 + g*8 + j];
    wf[8*64 + lane] = F;

    // hbias: [w][lane][r] so main does ONE dwordx4 per lane
    float* hb = ws + WS_HB;
    #pragma unroll
    for (int ww = 0; ww < 4; ++ww)
        #pragma unroll
        for (int r = 0; r < 4; ++r)
            hb[ww*256 + lane*4 + r] = proj_b[c] + pos[(ww*16 + g*4 + r)*16 + c];

    if (lane < 16) {
        float* ep = ws + WS_EP + lane*16;
        ep[0]  = in_proj_b[lane];              // q bias
        ep[1]  = in_proj_b[16 + lane] * SCALE; // k bias, pre-scaled
        ep[2]  = in_proj_b[32 + lane];         // v bias
        ep[3]  = out_b[lane];
        ep[4]  = ln1_g[lane];
        ep[5]  = ln1_b[lane];
        ep[6]  = lin1_b[lane];
        ep[7]  = lin1_b[16 + lane];
        ep[8]  = lin2_b[lane];
        ep[9]  = ln2_g[lane];
        ep[10] = ln2_b[lane];
        ep[11] = head_w[lane];
        ep[12] = 0.f; ep[13] = 0.f; ep[14] = 0.f; ep[15] = 0.f;
    }
}

__global__ __launch_bounds__(256, 8)
void tx_main(const float* __restrict__ x, const float* __restrict__ ws,
             const float* __restrict__ head_b, float* __restrict__ out)
{
    __shared__ __align__(16) short sm[SMTOT];
    const int tid   = threadIdx.x;
    const int w     = tid >> 6;
    const int lane  = tid & 63;
    const int g     = lane >> 4;
    const int c     = lane & 15;
    const int b     = blockIdx.x;
    const int myrow = w*16 + c;
    const int tok0  = w*16 + g*4;
    const v8bf* wf  = (const v8bf*)ws;
    const float4* ep4 = (const float4*)(ws + WS_EP);

    v8bf zfrag;
    #pragma unroll
    for (int j = 0; j < 8; ++j) zfrag[j] = (__bf16)0.f;
    const v4f zacc = {0.f, 0.f, 0.f, 0.f};

    // ---- zero pads (wave-local writes; read wave-locally / post-barrier) ----
    // HR cols 16..31 of my row (qkv A-frag K-pad)
    *(unsigned long long*)&sm[HRB + myrow*HRS + 16 + g*4] = 0ull;
    // KR cols 16..23 of my wave's rows (swapped-attn A-frags, g=2, read
    // cross-wave AFTER the barrier)
    if (lane < 16) {
        float4 z4 = {0.f, 0.f, 0.f, 0.f};
        *(float4*)&sm[(w*16 + lane)*KRS + 16] = z4;
    }

    // ---- proj: h = x @ proj_w^T, x loaded global->register (R8) ----
    v4f hC;
    {
        const float* xr = x + (size_t)b * 3136 + myrow*49;
        int off1 = 32 + g*8; if (off1 > 41) off1 = 41;   // bounds-safe chunk2
        v8bf a0, a1;
        #pragma unroll
        for (int j = 0; j < 8; ++j) a0[j] = (__bf16)xr[g*8 + j];
        #pragma unroll
        for (int j = 0; j < 8; ++j) a1[j] = (__bf16)xr[off1 + j];
        v4f hb = ((const v4f*)(ws + WS_HB))[w*64 + lane];   // one dwordx4
        hC = MFMA(a0, wf[0*64 + lane], hb);
        hC = MFMA(a1, wf[1*64 + lane], hC);
        #pragma unroll
        for (int r = 0; r < 4; ++r) sm[HRB + (tok0 + r)*HRS + c] = f2bs(hC[r]);
    }
    LDS_ORDER();   // h write -> qkv read is wave-local

    // ---- qkv = h @ in_proj_w^T + b; v written SLOT-PERMUTED ----
    {
        v8bf a = *(const v8bf*)&sm[HRB + myrow*HRS + g*8];
        v4f qC = MFMA(a, wf[2*64 + lane], zacc);
        v4f kC = MFMA(a, wf[3*64 + lane], zacc);
        v4f vC = MFMA(a, wf[4*64 + lane], zacc);
        float4 e0 = ep4[c*4];
        const int vsl = VTB + c*VTS + 32*(w >> 1) + 8*g + 4*(w & 1);
        #pragma unroll
        for (int r = 0; r < 4; ++r) {
            int tok = tok0 + r;
            sm[HRB + tok*HRS + c] = f2bs(qC[r] + e0.x);
            sm[tok*KRS + c]       = f2bs(fmaf(kC[r], SCALE, e0.y));
            sm[vsl + r]           = f2bs(vC[r] + e0.z);
        }
    }
    __syncthreads();   // the ONE barrier: k/V/KR-zero cross-wave visibility

    // ---- attention: swapped scores -> P in-register -> PV ----
    v4f ctxC0, ctxC1;
    {
        v8bf aq = *(const v8bf*)&sm[HRB + myrow*HRS + g*8];  // cols 16..31 zero
        #pragma unroll
        for (int hh = 0; hh < 2; ++hh) {
            v8bf bq = (g == hh) ? aq : zfrag;  // B rows = head hh's 8 features
            v8bf plo, phi;
            {
                v8bf ak0 = *(const v8bf*)&sm[(0*16 + c)*KRS + g*8];
                v8bf ak1 = *(const v8bf*)&sm[(1*16 + c)*KRS + g*8];
                v4f s0 = MFMA(ak0, bq, zacc);
                v4f s1 = MFMA(ak1, bq, zacc);
                #pragma unroll
                for (int r = 0; r < 4; ++r) {
                    plo[r]     = (__bf16)__builtin_amdgcn_exp2f(s0[r]);
                    plo[4 + r] = (__bf16)__builtin_amdgcn_exp2f(s1[r]);
                }
                v8bf ak2 = *(const v8bf*)&sm[(2*16 + c)*KRS + g*8];
                v8bf ak3 = *(const v8bf*)&sm[(3*16 + c)*KRS + g*8];
                v4f s2 = MFMA(ak2, bq, zacc);
                v4f s3 = MFMA(ak3, bq, zacc);
                #pragma unroll
                for (int r = 0; r < 4; ++r) {
                    phi[r]     = (__bf16)__builtin_amdgcn_exp2f(s2[r]);
                    phi[4 + r] = (__bf16)__builtin_amdgcn_exp2f(s3[r]);
                }
            }
            // V (slot-permuted) + ones column for softmax denominator
            v8bf bv0 = zfrag, bv1 = zfrag;
            bool act  = (hh == 0) ? (c < 8) : (c >= 8);
            int  onec = (hh == 0) ? 8 : 7;
            if (act) {
                bv0 = *(const v8bf*)&sm[VTB + c*VTS + g*8];
                bv1 = *(const v8bf*)&sm[VTB + c*VTS + 32 + g*8];
            } else if (c == onec) {
                #pragma unroll
                for (int j = 0; j < 8; ++j) { bv0[j] = (__bf16)1.f; bv1[j] = (__bf16)1.f; }
            }
            v4f acc = MFMA(plo, bv0, zacc);
            acc = MFMA(phi, bv1, acc);
            if (hh) ctxC1 = acc; else ctxC0 = acc;
        }
    }

    // ---- softmax normalize (l broadcast via ds_swizzle; v_rcp not div) ----
    {
        #pragma unroll
        for (int r = 0; r < 4; ++r) {
            float l0 = swz<0x110>(ctxC0[r]);   // from lane (lane&48)|8
            float l1 = swz<0x0F0>(ctxC1[r]);   // from lane (lane&48)|7
            float num = (c < 8) ? ctxC0[r] : ctxC1[r];
            float den = (c < 8) ? l0 : l1;
            sm[HRB + (tok0 + r)*HRS + c] = f2bs(num * __builtin_amdgcn_rcpf(den));
        }
    }
    LDS_ORDER();

    // ---- out-proj (+hC via C-input) + LN1 (E[x^2]-E[x]^2) ----
    v4f hln;
    {
        v8bf a = *(const v8bf*)&sm[HRB + myrow*HRS + g*8];
        v4f oC = MFMA(a, wf[5*64 + lane], hC);   // = hC + ctx@out_w^T
        float4 e0 = ep4[c*4];
        float4 e1 = ep4[c*4 + 1];
        v4f hn, s, q;
        #pragma unroll
        for (int r = 0; r < 4; ++r) { hn[r] = oC[r] + e0.w; s[r] = hn[r]; q[r] = hn[r]*hn[r]; }
        red16(s);
        red16(q);
        #pragma unroll
        for (int r = 0; r < 4; ++r) {
            float mean = s[r]*0.0625f;
            float is = __builtin_amdgcn_rsqf(fmaf(q[r], 0.0625f, fmaf(mean, -mean, 1e-5f)));
            hln[r] = (hn[r] - mean)*is*e1.x + e1.y;
            sm[HRB + (tok0 + r)*HRS + c] = f2bs(hln[r]);
        }
    }
    LDS_ORDER();

    // ---- FFN: lin1(+bias,relu) -> lin2 (K=32, hln folded into C) ----
    v4f o2;
    {
        v8bf a = *(const v8bf*)&sm[HRB + myrow*HRS + g*8];
        v4f f0 = MFMA(a, wf[6*64 + lane], zacc);
        v4f f1 = MFMA(a, wf[7*64 + lane], zacc);
        float4 e1 = ep4[c*4 + 1];
        #pragma unroll
        for (int r = 0; r < 4; ++r) {
            int tok = tok0 + r;
            sm[HRB + tok*HRS + c]      = f2bs(fmaxf(f0[r] + e1.z, 0.f));
            sm[HRB + tok*HRS + 16 + c] = f2bs(fmaxf(f1[r] + e1.w, 0.f));
        }
        LDS_ORDER();
        v8bf a2 = *(const v8bf*)&sm[HRB + myrow*HRS + g*8];
        o2 = MFMA(a2, wf[8*64 + lane], hln);     // = hln + ff@lin2_w^T
    }

    // ---- +lin2_b, LN2 (same var trick), head dot; wave + x-wave reduce ----
    float part = 0.f;
    {
        float4 e2 = ep4[c*4 + 2];
        v4f hn, s, q;
        #pragma unroll
        for (int r = 0; r < 4; ++r) { hn[r] = o2[r] + e2.x; s[r] = hn[r]; q[r] = hn[r]*hn[r]; }
        red16(s);
        red16(q);
        #pragma unroll
        for (int r = 0; r < 4; ++r) {
            float mean = s[r]*0.0625f;
            float is = __builtin_amdgcn_rsqf(fmaf(q[r], 0.0625f, fmaf(mean, -mean, 1e-5f)));
            float h3 = (hn[r] - mean)*is*e2.y + e2.z;
            part = fmaf(h3, e2.w, part);
        }
    }
    part += swz<0x041F>(part);
    part += swz<0x081F>(part);
    part += swz<0x101F>(part);
    part += swz<0x201F>(part);
    part += swz<0x401F>(part);
    part += __shfl_xor(part, 32, 64);
    float* fred = (float*)&sm[RED];
    if (lane == 0) fred[w] = part;
    __syncthreads();
    if (tid == 0)
        out[b] = (fred[0] + fred[1] + fred[2] + fred[3]) * (1.f/64.f) + head_b[0];
}

extern "C" void kernel_launch(void* const* d_in, const int* in_sizes, int n_in,
                              void* d_out, int out_size, void* d_ws, size_t ws_size,
                              hipStream_t stream) {
    const float* x         = (const float*)d_in[0];
    const float* proj_w    = (const float*)d_in[1];
    const float* proj_b    = (const float*)d_in[2];
    const float* pos       = (const float*)d_in[3];
    const float* in_proj_w = (const float*)d_in[4];
    const float* in_proj_b = (const float*)d_in[5];
    const float* out_w     = (const float*)d_in[6];
    const float* out_b     = (const float*)d_in[7];
    const float* ln1_g     = (const float*)d_in[8];
    const float* ln1_b     = (const float*)d_in[9];
    const float* lin1_w    = (const float*)d_in[10];
    const float* lin1_b    = (const float*)d_in[11];
    const float* lin2_w    = (const float*)d_in[12];
    const float* lin2_b    = (const float*)d_in[13];
    const float* ln2_g     = (const float*)d_in[14];
    const float* ln2_b     = (const float*)d_in[15];
    const float* head_w    = (const float*)d_in[16];
    const float* head_b    = (const float*)d_in[17];
    float* ws = (float*)d_ws;

    tx_prep<<<1, 64, 0, stream>>>(proj_w, proj_b, pos, in_proj_w, in_proj_b,
                                  out_w, out_b, ln1_g, ln1_b, lin1_w, lin1_b,
                                  lin2_w, lin2_b, ln2_g, ln2_b, head_w, ws);
    tx_main<<<16384, 256, 0, stream>>>(x, ws, head_b, (float*)d_out);
}

// Round 6
// 318.100 us; speedup vs baseline: 1.1597x; 1.0193x over previous
//
#include <hip/hip_runtime.h>

// TxModel: B=16384, K=64 tokens, DIN=49, D=16, NH=2, HD=8, FF=32
// Block = 256 threads = 4 waves, one batch element; wave w owns M-tile w.
// R10: R9 with the final-reduce swizzle fixed (0x201F=xor8 -> 0x401F=xor16;
// xor8 stays inside an already-reduced 16-group, computing 2(S0+S2) instead
// of S0+S1+S2+S3 -> R9's absmax failure).
//  (1) All 16-lane reductions (LN1, LN2, head-dot) use DPP rotate-reduce:
//      v_add_f32_dpp quad_perm(xor1), quad_perm(xor2), row_ror:4, row_ror:8.
//      Replaces 64 ds_swizzle + 64 adds per lane with 64 DPP adds: zero LDS
//      traffic, ~2cy/stage vs ~30cy ds_swizzle round trip (serial chains).
//  (2) tx_prep: 256 threads, work split by wave -> 4x memory-level
//      parallelism on its latency-bound scattered loads.
// Carried from R8: global->register x loads with remapped chunk2 weights, one
// barrier total, in-register P via swapped scores + slot-permuted V, folded
// biases in MFMA C-inputs, k pre-scaled, rcp/exp2/rsq natives,
// E[x^2]-E[x]^2 LNs.

#define SCALE 0.510069729f   // log2(e)/sqrt(8)

// LDS layout (short indices):
//   KR  [64][24] bf16 k rows (cols 16..23 zeroed)  [0,1536)
//   VTB [16][72] bf16 v^T, slot-permuted           [1536,2688)
//   HR  [64][40] bf16 h/q/ctx/hln/ff rows          [2688,5248)
//   RED 4 floats                                   [5248,5256)
#define KRS   24
#define VTB   1536
#define VTS   72
#define HRB   2688
#define HRS   40
#define RED   5248
#define SMTOT 5256   // 10512 B

// ws layout (floats): [0,2304) 9 weight B-frags (v8bf: frag*64+lane)
//                     [2304,3328) hbias [w][lane][r] = proj_b[c]+pos[tok][c]
//                     [3328,3584) epil  [c][16]   (ep[1] pre-scaled by SCALE)
#define WS_HB   2304
#define WS_EP   3328

typedef __bf16 v8bf __attribute__((ext_vector_type(8)));
typedef float  v4f  __attribute__((ext_vector_type(4)));

#define LDS_ORDER() __asm__ volatile("" ::: "memory")

static __device__ __forceinline__ short f2bs(float f) {
    __bf16 h = (__bf16)f;
    return __builtin_bit_cast(short, h);
}
#define MFMA(a,b,c) __builtin_amdgcn_mfma_f32_16x16x32_bf16((a),(b),(c),0,0,0)

// ds_swizzle, compile-time pattern. BitMode offset=(xor<<10)|(or<<5)|and.
// Kept only where DPP can't reach: xor16 (0x401F) and (lane&48)|N broadcasts.
template<int IMM> static __device__ __forceinline__ float swz(float x) {
    return __builtin_bit_cast(float,
        __builtin_amdgcn_ds_swizzle(__builtin_bit_cast(int, x), IMM));
}

// DPP-fused add: v += dpp_shuffle(v). CTRL: 0xB1=quad_perm(1,0,3,2)=xor1,
// 0x4E=quad_perm(2,3,0,1)=xor2, 0x124=row_ror:4, 0x128=row_ror:8.
template<int CTRL> static __device__ __forceinline__ float dppadd(float v) {
    int t = __builtin_amdgcn_update_dpp(0, __builtin_bit_cast(int, v),
                                        CTRL, 0xF, 0xF, true);
    return v + __builtin_bit_cast(float, t);
}

// Sum over the 16 lanes of each row (c-group): quad butterfly then
// rotate-reduce (valid once quads are uniform). All VALU, no LDS.
static __device__ __forceinline__ void red16(v4f& v) {
    #pragma unroll
    for (int r = 0; r < 4; ++r) v[r] = dppadd<0xB1>(v[r]);
    #pragma unroll
    for (int r = 0; r < 4; ++r) v[r] = dppadd<0x4E>(v[r]);
    #pragma unroll
    for (int r = 0; r < 4; ++r) v[r] = dppadd<0x124>(v[r]);
    #pragma unroll
    for (int r = 0; r < 4; ++r) v[r] = dppadd<0x128>(v[r]);
}

__global__ __launch_bounds__(256)
void tx_prep(const float* __restrict__ proj_w, const float* __restrict__ proj_b,
             const float* __restrict__ pos,
             const float* __restrict__ in_proj_w, const float* __restrict__ in_proj_b,
             const float* __restrict__ out_w, const float* __restrict__ out_b,
             const float* __restrict__ ln1_g, const float* __restrict__ ln1_b,
             const float* __restrict__ lin1_w, const float* __restrict__ lin1_b,
             const float* __restrict__ lin2_w, const float* __restrict__ lin2_b,
             const float* __restrict__ ln2_g, const float* __restrict__ ln2_b,
             const float* __restrict__ head_w, float* __restrict__ ws)
{
    const int tid = threadIdx.x;
    const int wv = tid >> 6, lane = tid & 63;
    const int g = lane >> 4, c = lane & 15;
    v8bf* wf = (v8bf*)ws;
    v8bf F;
    if (wv == 0) {
        #pragma unroll
        for (int j = 0; j < 8; ++j) F[j] = (__bf16)proj_w[c*49 + g*8 + j];
        wf[0*64 + lane] = F;
        // remapped K-chunk2: g=0 -> k=32+j; g=1 -> k=40+j; g=2 -> only j==7
        // live (k=48); g=3 -> dead (A side loads col min(32+g*8,41)).
        #pragma unroll
        for (int j = 0; j < 8; ++j) {
            int k = (g == 0) ? (32 + j) : (g == 1) ? (40 + j)
                  : (g == 2 && j == 7) ? 48 : -1;
            F[j] = (k >= 0) ? (__bf16)proj_w[c*49 + k] : (__bf16)0.f;
        }
        wf[1*64 + lane] = F;
        #pragma unroll
        for (int nt = 0; nt < 3; ++nt) {
            #pragma unroll
            for (int j = 0; j < 8; ++j) { int k = g*8 + j; F[j] = (k < 16) ? (__bf16)in_proj_w[(nt*16 + c)*16 + k] : (__bf16)0.f; }
            wf[(2 + nt)*64 + lane] = F;
        }
    } else if (wv == 1) {
        #pragma unroll
        for (int j = 0; j < 8; ++j) { int k = g*8 + j; F[j] = (k < 16) ? (__bf16)out_w[c*16 + k] : (__bf16)0.f; }
        wf[5*64 + lane] = F;
        #pragma unroll
        for (int nt = 0; nt < 2; ++nt) {
            #pragma unroll
            for (int j = 0; j < 8; ++j) { int k = g*8 + j; F[j] = (k < 16) ? (__bf16)lin1_w[(nt*16 + c)*16 + k] : (__bf16)0.f; }
            wf[(6 + nt)*64 + lane] = F;
        }
        #pragma unroll
        for (int j = 0; j < 8; ++j) F[j] = (__bf16)lin2_w[c*32 + g*8 + j];
        wf[8*64 + lane] = F;
        if (lane < 16) {
            float* ep = ws + WS_EP + lane*16;
            ep[0]  = in_proj_b[lane];              // q bias
            ep[1]  = in_proj_b[16 + lane] * SCALE; // k bias, pre-scaled
            ep[2]  = in_proj_b[32 + lane];         // v bias
            ep[3]  = out_b[lane];
            ep[4]  = ln1_g[lane];
            ep[5]  = ln1_b[lane];
            ep[6]  = lin1_b[lane];
            ep[7]  = lin1_b[16 + lane];
            ep[8]  = lin2_b[lane];
            ep[9]  = ln2_g[lane];
            ep[10] = ln2_b[lane];
            ep[11] = head_w[lane];
            ep[12] = 0.f; ep[13] = 0.f; ep[14] = 0.f; ep[15] = 0.f;
        }
    } else {
        // hbias: [w][lane][r]; waves 2,3 take ww = {0,1} / {2,3}
        float* hb = ws + WS_HB;
        const int w0 = (wv - 2) * 2;
        #pragma unroll
        for (int i = 0; i < 2; ++i) {
            int ww = w0 + i;
            #pragma unroll
            for (int r = 0; r < 4; ++r)
                hb[ww*256 + lane*4 + r] = proj_b[c] + pos[(ww*16 + g*4 + r)*16 + c];
        }
    }
}

__global__ __launch_bounds__(256, 8)
void tx_main(const float* __restrict__ x, const float* __restrict__ ws,
             const float* __restrict__ head_b, float* __restrict__ out)
{
    __shared__ __align__(16) short sm[SMTOT];
    const int tid   = threadIdx.x;
    const int w     = tid >> 6;
    const int lane  = tid & 63;
    const int g     = lane >> 4;
    const int c     = lane & 15;
    const int b     = blockIdx.x;
    const int myrow = w*16 + c;
    const int tok0  = w*16 + g*4;
    const v8bf* wf  = (const v8bf*)ws;
    const float4* ep4 = (const float4*)(ws + WS_EP);

    v8bf zfrag;
    #pragma unroll
    for (int j = 0; j < 8; ++j) zfrag[j] = (__bf16)0.f;
    const v4f zacc = {0.f, 0.f, 0.f, 0.f};

    // ---- zero pads (wave-local writes; read wave-locally / post-barrier) ----
    *(unsigned long long*)&sm[HRB + myrow*HRS + 16 + g*4] = 0ull;
    if (lane < 16) {
        float4 z4 = {0.f, 0.f, 0.f, 0.f};
        *(float4*)&sm[(w*16 + lane)*KRS + 16] = z4;
    }

    // ---- proj: h = x @ proj_w^T, x loaded global->register ----
    v4f hC;
    {
        const float* xr = x + (size_t)b * 3136 + myrow*49;
        int off1 = 32 + g*8; if (off1 > 41) off1 = 41;   // bounds-safe chunk2
        v8bf a0, a1;
        #pragma unroll
        for (int j = 0; j < 8; ++j) a0[j] = (__bf16)xr[g*8 + j];
        #pragma unroll
        for (int j = 0; j < 8; ++j) a1[j] = (__bf16)xr[off1 + j];
        v4f hb = ((const v4f*)(ws + WS_HB))[w*64 + lane];   // one dwordx4
        hC = MFMA(a0, wf[0*64 + lane], hb);
        hC = MFMA(a1, wf[1*64 + lane], hC);
        #pragma unroll
        for (int r = 0; r < 4; ++r) sm[HRB + (tok0 + r)*HRS + c] = f2bs(hC[r]);
    }
    LDS_ORDER();   // h write -> qkv read is wave-local

    // ---- qkv = h @ in_proj_w^T + b; v written SLOT-PERMUTED ----
    {
        v8bf a = *(const v8bf*)&sm[HRB + myrow*HRS + g*8];
        v4f qC = MFMA(a, wf[2*64 + lane], zacc);
        v4f kC = MFMA(a, wf[3*64 + lane], zacc);
        v4f vC = MFMA(a, wf[4*64 + lane], zacc);
        float4 e0 = ep4[c*4];
        const int vsl = VTB + c*VTS + 32*(w >> 1) + 8*g + 4*(w & 1);
        #pragma unroll
        for (int r = 0; r < 4; ++r) {
            int tok = tok0 + r;
            sm[HRB + tok*HRS + c] = f2bs(qC[r] + e0.x);
            sm[tok*KRS + c]       = f2bs(fmaf(kC[r], SCALE, e0.y));
            sm[vsl + r]           = f2bs(vC[r] + e0.z);
        }
    }
    __syncthreads();   // the ONE barrier: k/V/KR-zero cross-wave visibility

    // ---- attention: swapped scores -> P in-register -> PV ----
    v4f ctxC0, ctxC1;
    {
        v8bf aq = *(const v8bf*)&sm[HRB + myrow*HRS + g*8];  // cols 16..31 zero
        #pragma unroll
        for (int hh = 0; hh < 2; ++hh) {
            v8bf bq = (g == hh) ? aq : zfrag;  // B rows = head hh's 8 features
            v8bf plo, phi;
            {
                v8bf ak0 = *(const v8bf*)&sm[(0*16 + c)*KRS + g*8];
                v8bf ak1 = *(const v8bf*)&sm[(1*16 + c)*KRS + g*8];
                v4f s0 = MFMA(ak0, bq, zacc);
                v4f s1 = MFMA(ak1, bq, zacc);
                #pragma unroll
                for (int r = 0; r < 4; ++r) {
                    plo[r]     = (__bf16)__builtin_amdgcn_exp2f(s0[r]);
                    plo[4 + r] = (__bf16)__builtin_amdgcn_exp2f(s1[r]);
                }
                v8bf ak2 = *(const v8bf*)&sm[(2*16 + c)*KRS + g*8];
                v8bf ak3 = *(const v8bf*)&sm[(3*16 + c)*KRS + g*8];
                v4f s2 = MFMA(ak2, bq, zacc);
                v4f s3 = MFMA(ak3, bq, zacc);
                #pragma unroll
                for (int r = 0; r < 4; ++r) {
                    phi[r]     = (__bf16)__builtin_amdgcn_exp2f(s2[r]);
                    phi[4 + r] = (__bf16)__builtin_amdgcn_exp2f(s3[r]);
                }
            }
            // V (slot-permuted) + ones column for softmax denominator
            v8bf bv0 = zfrag, bv1 = zfrag;
            bool act  = (hh == 0) ? (c < 8) : (c >= 8);
            int  onec = (hh == 0) ? 8 : 7;
            if (act) {
                bv0 = *(const v8bf*)&sm[VTB + c*VTS + g*8];
                bv1 = *(const v8bf*)&sm[VTB + c*VTS + 32 + g*8];
            } else if (c == onec) {
                #pragma unroll
                for (int j = 0; j < 8; ++j) { bv0[j] = (__bf16)1.f; bv1[j] = (__bf16)1.f; }
            }
            v4f acc = MFMA(plo, bv0, zacc);
            acc = MFMA(phi, bv1, acc);
            if (hh) ctxC1 = acc; else ctxC0 = acc;
        }
    }

    // ---- softmax normalize (l broadcast via ds_swizzle; v_rcp not div) ----
    {
        #pragma unroll
        for (int r = 0; r < 4; ++r) {
            float l0 = swz<0x110>(ctxC0[r]);   // from lane (lane&48)|8
            float l1 = swz<0x0F0>(ctxC1[r]);   // from lane (lane&48)|7
            float num = (c < 8) ? ctxC0[r] : ctxC1[r];
            float den = (c < 8) ? l0 : l1;
            sm[HRB + (tok0 + r)*HRS + c] = f2bs(num * __builtin_amdgcn_rcpf(den));
        }
    }
    LDS_ORDER();

    // ---- out-proj (+hC via C-input) + LN1 (E[x^2]-E[x]^2, DPP reduce) ----
    v4f hln;
    {
        v8bf a = *(const v8bf*)&sm[HRB + myrow*HRS + g*8];
        v4f oC = MFMA(a, wf[5*64 + lane], hC);   // = hC + ctx@out_w^T
        float4 e0 = ep4[c*4];
        float4 e1 = ep4[c*4 + 1];
        v4f hn, s, q;
        #pragma unroll
        for (int r = 0; r < 4; ++r) { hn[r] = oC[r] + e0.w; s[r] = hn[r]; q[r] = hn[r]*hn[r]; }
        red16(s);
        red16(q);
        #pragma unroll
        for (int r = 0; r < 4; ++r) {
            float mean = s[r]*0.0625f;
            float is = __builtin_amdgcn_rsqf(fmaf(q[r], 0.0625f, fmaf(mean, -mean, 1e-5f)));
            hln[r] = (hn[r] - mean)*is*e1.x + e1.y;
            sm[HRB + (tok0 + r)*HRS + c] = f2bs(hln[r]);
        }
    }
    LDS_ORDER();

    // ---- FFN: lin1(+bias,relu) -> lin2 (K=32, hln folded into C) ----
    v4f o2;
    {
        v8bf a = *(const v8bf*)&sm[HRB + myrow*HRS + g*8];
        v4f f0 = MFMA(a, wf[6*64 + lane], zacc);
        v4f f1 = MFMA(a, wf[7*64 + lane], zacc);
        float4 e1 = ep4[c*4 + 1];
        #pragma unroll
        for (int r = 0; r < 4; ++r) {
            int tok = tok0 + r;
            sm[HRB + tok*HRS + c]      = f2bs(fmaxf(f0[r] + e1.z, 0.f));
            sm[HRB + tok*HRS + 16 + c] = f2bs(fmaxf(f1[r] + e1.w, 0.f));
        }
        LDS_ORDER();
        v8bf a2 = *(const v8bf*)&sm[HRB + myrow*HRS + g*8];
        o2 = MFMA(a2, wf[8*64 + lane], hln);     // = hln + ff@lin2_w^T
    }

    // ---- +lin2_b, LN2 (DPP reduce), head dot; wave + x-wave reduce ----
    float part = 0.f;
    {
        float4 e2 = ep4[c*4 + 2];
        v4f hn, s, q;
        #pragma unroll
        for (int r = 0; r < 4; ++r) { hn[r] = o2[r] + e2.x; s[r] = hn[r]; q[r] = hn[r]*hn[r]; }
        red16(s);
        red16(q);
        #pragma unroll
        for (int r = 0; r < 4; ++r) {
            float mean = s[r]*0.0625f;
            float is = __builtin_amdgcn_rsqf(fmaf(q[r], 0.0625f, fmaf(mean, -mean, 1e-5f)));
            float h3 = (hn[r] - mean)*is*e2.y + e2.z;
            part = fmaf(h3, e2.w, part);
        }
    }
    // 64-lane sum: DPP within 16, then xor16 (0x401F!), then cross-32
    part = dppadd<0xB1>(part);
    part = dppadd<0x4E>(part);
    part = dppadd<0x124>(part);
    part = dppadd<0x128>(part);
    part += swz<0x401F>(part);          // xor16 (R9 bug: 0x201F = xor8)
    part += __shfl_xor(part, 32, 64);
    float* fred = (float*)&sm[RED];
    if (lane == 0) fred[w] = part;
    __syncthreads();
    if (tid == 0)
        out[b] = (fred[0] + fred[1] + fred[2] + fred[3]) * (1.f/64.f) + head_b[0];
}

extern "C" void kernel_launch(void* const* d_in, const int* in_sizes, int n_in,
                              void* d_out, int out_size, void* d_ws, size_t ws_size,
                              hipStream_t stream) {
    const float* x         = (const float*)d_in[0];
    const float* proj_w    = (const float*)d_in[1];
    const float* proj_b    = (const float*)d_in[2];
    const float* pos       = (const float*)d_in[3];
    const float* in_proj_w = (const float*)d_in[4];
    const float* in_proj_b = (const float*)d_in[5];
    const float* out_w     = (const float*)d_in[6];
    const float* out_b     = (const float*)d_in[7];
    const float* ln1_g     = (const float*)d_in[8];
    const float* ln1_b     = (const float*)d_in[9];
    const float* lin1_w    = (const float*)d_in[10];
    const float* lin1_b    = (const float*)d_in[11];
    const float* lin2_w    = (const float*)d_in[12];
    const float* lin2_b    = (const float*)d_in[13];
    const float* ln2_g     = (const float*)d_in[14];
    const float* ln2_b     = (const float*)d_in[15];
    const float* head_w    = (const float*)d_in[16];
    const float* head_b    = (const float*)d_in[17];
    float* ws = (float*)d_ws;

    tx_prep<<<1, 256, 0, stream>>>(proj_w, proj_b, pos, in_proj_w, in_proj_b,
                                   out_w, out_b, ln1_g, ln1_b, lin1_w, lin1_b,
                                   lin2_w, lin2_b, ln2_g, ln2_b, head_w, ws);
    tx_main<<<16384, 256, 0, stream>>>(x, ws, head_b, (float*)d_out);
}